// Round 1
// baseline (750.242 us; speedup 1.0000x reference)
//
#include <hip/hip_runtime.h>

#define K_CLASSES 32
#define D 128

// ---------------------------------------------------------------------------
// Per-class Gram: ZtPiZ[k] = sum_{i : Y[i]==k} z_i z_i^T
// Grid: (NCHUNK, K). Each block scans a row-chunk for class-k samples,
// compacts indices to LDS, stages 8 rows at a time, accumulates 8x8 register
// tiles per thread, then atomically adds its partial into the output.
// ---------------------------------------------------------------------------
__global__ __launch_bounds__(256) void gram_kernel(const float* __restrict__ Z,
                                                   const int* __restrict__ Y,
                                                   float* __restrict__ ztpiz,
                                                   int* __restrict__ counts,
                                                   int m, int chunkRows) {
  const int k = blockIdx.y;
  const int rowStart = blockIdx.x * chunkRows;
  __shared__ int list[2048];
  __shared__ float zrows[8][D];
  __shared__ int cnt;

  float acc[64];
#pragma unroll
  for (int i = 0; i < 64; ++i) acc[i] = 0.f;

  const int tr = (threadIdx.x >> 4) << 3;   // row-tile base (0..120 step 8)
  const int tc = (threadIdx.x & 15) << 3;   // col-tile base (0..120 step 8)

  int matched = 0;
  for (int sub = 0; sub < chunkRows; sub += 2048) {
    if (threadIdx.x == 0) cnt = 0;
    __syncthreads();
    for (int i = threadIdx.x; i < 2048; i += 256) {
      const int row = rowStart + sub + i;
      if (row < m && Y[row] == k) {
        const int p = atomicAdd(&cnt, 1);
        list[p] = row;
      }
    }
    __syncthreads();
    const int n = cnt;
    matched += n;
    for (int t0 = 0; t0 < n; t0 += 8) {
      // stage up to 8 rows: each 32-thread group loads one contiguous row
      const int s = threadIdx.x >> 5;
      const int off = (threadIdx.x & 31) << 2;
      if (t0 + s < n) {
        const int row = list[t0 + s];
        const float4 v = *(const float4*)(Z + (size_t)row * D + off);
        *(float4*)(&zrows[s][off]) = v;
      }
      __syncthreads();
      const int nb = min(8, n - t0);
      for (int ss = 0; ss < nb; ++ss) {
        float zr[8], zc[8];
        *(float4*)(zr)     = *(const float4*)(&zrows[ss][tr]);
        *(float4*)(zr + 4) = *(const float4*)(&zrows[ss][tr + 4]);
        *(float4*)(zc)     = *(const float4*)(&zrows[ss][tc]);
        *(float4*)(zc + 4) = *(const float4*)(&zrows[ss][tc + 4]);
#pragma unroll
        for (int i = 0; i < 8; ++i)
#pragma unroll
          for (int j = 0; j < 8; ++j)
            acc[i * 8 + j] = fmaf(zr[i], zc[j], acc[i * 8 + j]);
      }
      __syncthreads();
    }
    __syncthreads();
  }

  float* dst = ztpiz + (size_t)k * D * D;
#pragma unroll
  for (int i = 0; i < 8; ++i)
#pragma unroll
    for (int j = 0; j < 8; ++j)
      atomicAdd(&dst[(tr + i) * D + (tc + j)], acc[i * 8 + j]);
  if (threadIdx.x == 0) atomicAdd(&counts[k], matched);
}

// ---------------------------------------------------------------------------
// Column sums of Z (for Z_mean)
// ---------------------------------------------------------------------------
__global__ __launch_bounds__(256) void colsum_kernel(const float* __restrict__ Z,
                                                     float* __restrict__ colsum,
                                                     int m) {
  __shared__ float red[256];
  const int c = threadIdx.x & 127;
  const int half = threadIdx.x >> 7;
  float s = 0.f;
  for (int r = blockIdx.x * 2 + half; r < m; r += gridDim.x * 2)
    s += Z[(size_t)r * D + c];
  red[threadIdx.x] = s;
  __syncthreads();
  if (threadIdx.x < 128)
    atomicAdd(&colsum[c], red[threadIdx.x] + red[threadIdx.x + 128]);
}

// ---------------------------------------------------------------------------
// gram = sum_k ZtPiZ[k]  (classes partition the samples, so this is Z^T Z)
// ---------------------------------------------------------------------------
__global__ void sum_gram_kernel(const float* __restrict__ ztpiz,
                                float* __restrict__ gram) {
  const int e = blockIdx.x * blockDim.x + threadIdx.x;
  if (e < D * D) {
    float s = 0.f;
#pragma unroll
    for (int k = 0; k < K_CLASSES; ++k) s += ztpiz[k * D * D + e];
    gram[e] = s;
  }
}

// ---------------------------------------------------------------------------
// logdet via in-LDS Cholesky of I + s*G, one block per matrix.
// Block 0: discriminative matrix (full gram). Blocks 1..32: per-class.
// ---------------------------------------------------------------------------
__global__ __launch_bounds__(128) void chol_kernel(const float* __restrict__ ztpiz,
                                                   const float* __restrict__ gram,
                                                   const int* __restrict__ counts,
                                                   float* __restrict__ ld, int m) {
  const int b = blockIdx.x;
  __shared__ float A[D][D + 1];
  __shared__ float red[128];
  const float* src;
  float s;
  if (b == 0) {
    src = gram;
    s = (float)D / ((float)m * 0.5f);           // GAM1 * d/(m*eps)
  } else {
    src = ztpiz + (size_t)(b - 1) * D * D;
    const float cf = (float)counts[b - 1] + 1e-8f;
    s = (float)D / (cf * 0.5f);                 // d/(num_k*eps)
  }
  for (int e = threadIdx.x; e < D * D; e += 128) {
    const int r = e >> 7, c = e & 127;
    A[r][c] = s * src[e] + ((r == c) ? 1.0f : 0.0f);
  }
  __syncthreads();

  for (int k = 0; k < D; ++k) {
    if (threadIdx.x == 0) A[k][k] = sqrtf(A[k][k]);
    __syncthreads();
    const float inv = 1.0f / A[k][k];
    for (int j = k + 1 + threadIdx.x; j < D; j += 128) A[j][k] *= inv;
    __syncthreads();
    for (int i = k + 1 + threadIdx.x; i < D; i += 128) {
      const float lik = A[i][k];
      for (int j = k + 1; j <= i; ++j) A[i][j] -= lik * A[j][k];
    }
    __syncthreads();
  }

  float lsum = logf(A[threadIdx.x][threadIdx.x]);
  red[threadIdx.x] = lsum;
  __syncthreads();
  for (int off = 64; off > 0; off >>= 1) {
    if (threadIdx.x < off) red[threadIdx.x] += red[threadIdx.x + off];
    __syncthreads();
  }
  if (threadIdx.x == 0) ld[b] = 2.0f * red[0];
}

// ---------------------------------------------------------------------------
// Assemble loss and Z_mean
// ---------------------------------------------------------------------------
__global__ void finalize_kernel(const float* __restrict__ ldv,
                                const int* __restrict__ counts,
                                const float* __restrict__ colsum,
                                float* __restrict__ out, int m) {
  const int t = threadIdx.x;
  if (t < D) out[1 + K_CLASSES * D * D + t] = colsum[t] / (float)m;
  if (t == 0) {
    float compress = 0.f;
    for (int k = 0; k < K_CLASSES; ++k)
      compress += ldv[k + 1] * (((float)counts[k] + 1e-8f) / (float)m);
    compress *= 0.5f;
    const float discrim = 0.5f * ldv[0];
    out[0] = -discrim + compress;   // GAM2 = 1
  }
}

extern "C" void kernel_launch(void* const* d_in, const int* in_sizes, int n_in,
                              void* d_out, int out_size, void* d_ws, size_t ws_size,
                              hipStream_t stream) {
  const float* Z = (const float*)d_in[0];
  const int* Y = (const int*)d_in[1];
  float* out = (float*)d_out;
  const int m = in_sizes[0] / D;

  // workspace layout
  int* counts = (int*)d_ws;                              // 32 ints
  float* colsum = (float*)((char*)d_ws + 128);           // 128 floats
  float* ld = (float*)((char*)d_ws + 640);               // 33 floats
  float* gram = (float*)((char*)d_ws + 4096);            // 16384 floats

  float* ztpiz = out + 1;                                // (K, D, D)

  hipMemsetAsync(d_out, 0, (size_t)out_size * sizeof(float), stream);
  hipMemsetAsync(d_ws, 0, 1024, stream);

  const int nchunk = 16;
  int chunkRows = (m + nchunk - 1) / nchunk;
  chunkRows = (chunkRows + 2047) & ~2047;

  gram_kernel<<<dim3(nchunk, K_CLASSES), 256, 0, stream>>>(Z, Y, ztpiz, counts, m, chunkRows);
  colsum_kernel<<<256, 256, 0, stream>>>(Z, colsum, m);
  sum_gram_kernel<<<(D * D + 255) / 256, 256, 0, stream>>>(ztpiz, gram);
  chol_kernel<<<K_CLASSES + 1, 128, 0, stream>>>(ztpiz, gram, counts, ld, m);
  finalize_kernel<<<1, 128, 0, stream>>>(ld, counts, colsum, out, m);
}